// Round 3
// baseline (179.384 us; speedup 1.0000x reference)
//
#include <hip/hip_runtime.h>

// ExpertMLP flat-K formulation:
//   h   = (coef[b,e]*x[b,i]) @ W1flat[(e,i),h] + coef@b1   (K = 4096)
//   h1  = elu(BN(h)); out = (coef[b,e]*h1[b,c]) @ W2flat + coef@b2
// 3 kernels: prep (W transposes), gemm1 (fused blend-A + stats partials),
// gemm2 (fused BN+ELU+blend-A). No atomics, no intermediate y/partial buffers.

typedef short bf16x8 __attribute__((ext_vector_type(8)));
typedef float f32x4 __attribute__((ext_vector_type(4)));
typedef unsigned short u16;
typedef u16 u16x4 __attribute__((ext_vector_type(4)));
typedef u16 u16x8 __attribute__((ext_vector_type(8)));

__device__ __forceinline__ u16 f2bf(float f) {
  union { float f; unsigned u; } v; v.f = f;
  return (u16)((v.u + 0x7FFFu + ((v.u >> 16) & 1u)) >> 16);  // RNE
}

#define AS_G(p) ((const __attribute__((address_space(1))) void*)(p))
#define AS_L(p) ((__attribute__((address_space(3))) void*)(p))

// ---------------- prep: w1,w2 (f32 [e][512k][512n]) -> bf16 Wt[512n][4096]
//                  where flat-k = e*512 + k ------------------------------
__global__ __launch_bounds__(256) void prep_kernel(
    const float* __restrict__ w1, const float* __restrict__ w2,
    u16* __restrict__ w1t, u16* __restrict__ w2t)
{
  int bid = blockIdx.x, t = threadIdx.x;
  __shared__ float ld[64][65];               // +1 pad breaks col-read conflicts
  const float* src = (bid >> 9) ? w2 : w1;
  u16* dst = (bid >> 9) ? w2t : w1t;
  int rem = bid & 511;
  int e = rem >> 6, tl = rem & 63;
  int kt = tl >> 3, nt = tl & 7;             // 64x64 tile at (kt,nt)
  #pragma unroll
  for (int j = 0; j < 4; ++j) {              // read [k][n] coalesced
    int kr = j * 16 + (t >> 4), nc = (t & 15) * 4;
    f32x4 v = *(const f32x4*)(src + (size_t)((e * 512 + kt * 64 + kr)) * 512 + nt * 64 + nc);
    ld[kr][nc] = v.x; ld[kr][nc + 1] = v.y; ld[kr][nc + 2] = v.z; ld[kr][nc + 3] = v.w;
  }
  __syncthreads();
  #pragma unroll
  for (int j = 0; j < 4; ++j) {              // write [n][flat-k] coalesced, bf16
    int nr = j * 16 + (t >> 4), kc = (t & 15) * 4;
    u16x4 o;
    o.x = f2bf(ld[kc][nr]);     o.y = f2bf(ld[kc + 1][nr]);
    o.z = f2bf(ld[kc + 2][nr]); o.w = f2bf(ld[kc + 3][nr]);
    *(u16x4*)(dst + (size_t)(nt * 64 + nr) * 4096 + e * 512 + kt * 64 + kc) = o;
  }
}

// ---------------- fused flat-K GEMM --------------------------------------
// tile 64(M)x64(N), BK=128, 256 thr = 4 waves (2x2), wave-tile 32x32.
// LAYER 1: A = f2bf(coef*x) packed in-register;  epilogue: h + blended bias,
//          per-mt column {sum,sumsq} partials (exclusive slots, no atomics).
// LAYER 2: pre-loop builds BN scale/shift from partials; A = f2bf(coef*elu(BN(h))).
template <int LAYER>
__global__ __launch_bounds__(256) void gemm_fused(
    const float* __restrict__ X,       // x [1024][512] or h [1024][512]
    const u16*  __restrict__ Wt,       // [512][4096] bf16
    const float* __restrict__ coef,    // [1024][8]
    const float* __restrict__ bias,    // b1 or b2 [8][512]
    const float* __restrict__ gamma, const float* __restrict__ beta,
    const float* __restrict__ sPin, const float* __restrict__ qPin,
    float* __restrict__ Out,           // h or out [1024][512]
    float* __restrict__ sPout, float* __restrict__ qPout)
{
  int raw = blockIdx.x;                       // 128 blocks, 2D XCD grouping
  int xcd = raw & 7, idx = raw >> 3;
  int mt = (xcd >> 1) * 4 + (idx >> 2);       // 0..15
  int nt = (xcd & 1) * 4 + (idx & 3);         // 0..7
  int t = threadIdx.x, l = t & 63, w = t >> 6;
  int wm = w >> 1, wn = w & 1;

  __shared__ alignas(16) u16 As[64 * 128];    // 16 KB
  __shared__ alignas(16) u16 Bs[2][64 * 128]; // 32 KB double-buffered
  __shared__ float scale_s[512], shift_s[512];
  __shared__ float red[4][2][2][16];          // [wave][sum/sq][n][col]

  if constexpr (LAYER == 2) {                 // reduce stats -> scale/shift
    for (int c = t; c < 512; c += 256) {
      float S = 0.f, Q = 0.f;
      #pragma unroll
      for (int p = 0; p < 16; ++p) { S += sPin[p * 512 + c]; Q += qPin[p * 512 + c]; }
      float mean = S * (1.0f / 1024.0f);
      float var  = Q * (1.0f / 1024.0f) - mean * mean;    // biased, matches ref
      float sc = gamma[c] * rsqrtf(var + 1e-5f);
      scale_s[c] = sc; shift_s[c] = beta[c] - mean * sc;
    }
    __syncthreads();
  }

  int arow = t >> 2, ac = t & 3;              // A-stage: row 0..63, 32k-chunk 0..3
  const float* xrow = X + (size_t)(mt * 64 + arow) * 512;
  const float* crow = coef + (size_t)(mt * 64 + arow) * 8;
  const u16* Bbase = Wt + (size_t)(nt * 64 + w * 4 + (l >> 4)) * 4096 + (l & 15) * 8;

  f32x4 acc[2][2] = {};
  f32x4 areg[8], scv[8], shv[8];
  int cur = 0;

  // prologue: issue A(0) reg loads + B(0) -> Bs[0]
  #pragma unroll
  for (int j = 0; j < 8; ++j) areg[j] = *(const f32x4*)(xrow + ac * 32 + j * 4);
  #pragma unroll
  for (int j = 0; j < 4; ++j)
    __builtin_amdgcn_global_load_lds(AS_G(Bbase + (size_t)j * 16 * 4096),
                                     AS_L(&Bs[0][(j * 16 + w * 4) * 128]), 16, 0, 0);

  for (int it = 0; it < 32; ++it) {           // it = phase*8 + e (K-order free)
    int phase = it >> 3, e = it & 7;
    if constexpr (LAYER == 2) {
      if ((it & 7) == 0) {                    // per-phase BN params for my 32 cols
        #pragma unroll
        for (int j = 0; j < 8; ++j) {
          scv[j] = *(const f32x4*)(scale_s + phase * 128 + ac * 32 + j * 4);
          shv[j] = *(const f32x4*)(shift_s + phase * 128 + ac * 32 + j * 4);
        }
      }
    }
    float cf = crow[e];
    // pack A(it): transform areg -> bf16, write to As
    #pragma unroll
    for (int q = 0; q < 4; ++q) {
      u16x8 av;
      #pragma unroll
      for (int half = 0; half < 2; ++half) {
        int j = q * 2 + half;
        f32x4 v = areg[j];
        #pragma unroll
        for (int i = 0; i < 4; ++i) {
          float val;
          if constexpr (LAYER == 1) {
            val = cf * v[i];
          } else {
            float hn = v[i] * scv[j][i] + shv[j][i];
            float el = hn > 0.0f ? hn : __expf(hn) - 1.0f;  // ELU(alpha=1)
            val = cf * el;
          }
          av[half * 4 + i] = f2bf(val);
        }
      }
      *(u16x8*)&As[arow * 128 + ac * 32 + q * 8] = av;
    }
    __syncthreads();                          // As ready; Bs[cur] drained
    if (it < 31) {                            // issue next tile (hidden by MFMA)
      int nit = it + 1, nphase = nit >> 3, ne = nit & 7;
      size_t nk0 = (size_t)ne * 512 + nphase * 128;
      #pragma unroll
      for (int j = 0; j < 8; ++j)
        areg[j] = *(const f32x4*)(xrow + nphase * 128 + ac * 32 + j * 4);
      #pragma unroll
      for (int j = 0; j < 4; ++j)
        __builtin_amdgcn_global_load_lds(AS_G(Bbase + (size_t)j * 16 * 4096 + nk0),
                                         AS_L(&Bs[cur ^ 1][(j * 16 + w * 4) * 128]), 16, 0, 0);
    }
    #pragma unroll
    for (int kk = 0; kk < 4; ++kk) {
      int ko = kk * 32 + (l >> 4) * 8;        // A/B frag: row=lane&15, k=8*(lane>>4)
      bf16x8 af[2], bb[2];
      #pragma unroll
      for (int m = 0; m < 2; ++m)
        af[m] = *(const bf16x8*)&As[(wm * 32 + m * 16 + (l & 15)) * 128 + ko];
      #pragma unroll
      for (int n = 0; n < 2; ++n)
        bb[n] = *(const bf16x8*)&Bs[cur][(wn * 32 + n * 16 + (l & 15)) * 128 + ko];
      #pragma unroll
      for (int m = 0; m < 2; ++m)
        #pragma unroll
        for (int n = 0; n < 2; ++n)
          acc[m][n] = __builtin_amdgcn_mfma_f32_16x16x32_bf16(af[m], bb[n], acc[m][n], 0, 0, 0);
    }
    __syncthreads();                          // As safe to rewrite next iter
    cur ^= 1;
  }

  // ---- epilogue: C/D layout col=lane&15, row=(lane>>4)*4+reg (HW-verified) ----
  int colg[2];
  #pragma unroll
  for (int n = 0; n < 2; ++n) colg[n] = nt * 64 + wn * 32 + n * 16 + (l & 15);
  float bcol[2][8];
  #pragma unroll
  for (int n = 0; n < 2; ++n)
    #pragma unroll
    for (int e = 0; e < 8; ++e) bcol[n][e] = bias[e * 512 + colg[n]];

  float sAcc[2] = {0.f, 0.f}, qAcc[2] = {0.f, 0.f};
  #pragma unroll
  for (int m = 0; m < 2; ++m) {
    int rbase = wm * 32 + m * 16 + (l >> 4) * 4;
    #pragma unroll
    for (int r = 0; r < 4; ++r) {
      int rowg = mt * 64 + rbase + r;
      f32x4 c0 = *(const f32x4*)(coef + (size_t)rowg * 8);
      f32x4 c1 = *(const f32x4*)(coef + (size_t)rowg * 8 + 4);
      #pragma unroll
      for (int n = 0; n < 2; ++n) {
        float bb = c0[0]*bcol[n][0] + c0[1]*bcol[n][1] + c0[2]*bcol[n][2] + c0[3]*bcol[n][3]
                 + c1[0]*bcol[n][4] + c1[1]*bcol[n][5] + c1[2]*bcol[n][6] + c1[3]*bcol[n][7];
        float v = acc[m][n][r] + bb;
        Out[(size_t)rowg * 512 + colg[n]] = v;
        if constexpr (LAYER == 1) { sAcc[n] += v; qAcc[n] += v * v; }
      }
    }
  }
  if constexpr (LAYER == 1) {                 // block-exclusive stats partials
    #pragma unroll
    for (int n = 0; n < 2; ++n) {
      sAcc[n] += __shfl_xor(sAcc[n], 16); sAcc[n] += __shfl_xor(sAcc[n], 32);
      qAcc[n] += __shfl_xor(qAcc[n], 16); qAcc[n] += __shfl_xor(qAcc[n], 32);
    }
    if (l < 16) {
      #pragma unroll
      for (int n = 0; n < 2; ++n) { red[w][0][n][l] = sAcc[n]; red[w][1][n][l] = qAcc[n]; }
    }
    __syncthreads();
    if (wm == 0 && l < 16) {                  // combine wm pair (w and w+2)
      #pragma unroll
      for (int n = 0; n < 2; ++n) {
        float S = red[w][0][n][l] + red[w + 2][0][n][l];
        float Q = red[w][1][n][l] + red[w + 2][1][n][l];
        sPout[mt * 512 + colg[n]] = S;
        qPout[mt * 512 + colg[n]] = Q;
      }
    }
  }
}

extern "C" void kernel_launch(void* const* d_in, const int* in_sizes, int n_in,
                              void* d_out, int out_size, void* d_ws, size_t ws_size,
                              hipStream_t stream)
{
  const float* x     = (const float*)d_in[0];
  const float* coef  = (const float*)d_in[1];
  const float* w1    = (const float*)d_in[2];
  const float* b1    = (const float*)d_in[3];
  const float* w2    = (const float*)d_in[4];
  const float* b2    = (const float*)d_in[5];
  const float* gamma = (const float*)d_in[6];
  const float* beta  = (const float*)d_in[7];
  float* out = (float*)d_out;

  char* ws = (char*)d_ws;
  u16* w1t  = (u16*)(ws);                          // 4 MB [512][4096] bf16
  u16* w2t  = (u16*)(ws + (4u << 20));             // 4 MB
  float* h  = (float*)(ws + (8u << 20));           // 2 MB [1024][512] f32
  float* sP = (float*)(ws + (10u << 20));          // 32 KB [16][512] col sums
  float* qP = (float*)(ws + (10u << 20) + 65536);  // 32 KB [16][512] col sumsq

  prep_kernel<<<1024, 256, 0, stream>>>(w1, w2, w1t, w2t);
  gemm_fused<1><<<128, 256, 0, stream>>>(x, w1t, coef, b1, gamma, beta,
                                         nullptr, nullptr, h, sP, qP);
  gemm_fused<2><<<128, 256, 0, stream>>>(h, w2t, coef, b2, gamma, beta,
                                         sP, qP, out, nullptr, nullptr);
}

// Round 4
// 67.590 us; speedup vs baseline: 2.6540x; 2.6540x over previous
//
#include <hip/hip_runtime.h>

// ExpertMLP: h = sum_e coef[b,e]*(x@w1[e]) + coef@b1 ; BN(batch); ELU;
//            out = sum_e coef[b,e]*(h1@w2[e]) + coef@b2
// R4: R2 expert-split structure + (a) XOR-swizzled LDS (pre-swizzled global
// source for global_load_lds, swizzled ds_read) -> conflict-free fragments,
// (b) 64x64 tiles -> 1024 blocks (4/CU), (c) BN+ELU fused into gemm2 A-stage
// (bnelu node + h1b round-trip removed). 5 graph nodes.

typedef short bf16x8 __attribute__((ext_vector_type(8)));
typedef float f32x4 __attribute__((ext_vector_type(4)));
typedef unsigned short u16;
typedef u16 u16x4 __attribute__((ext_vector_type(4)));
typedef u16 u16x8 __attribute__((ext_vector_type(8)));

__device__ __forceinline__ u16 f2bf(float f) {
  union { float f; unsigned u; } v; v.f = f;
  return (u16)((v.u + 0x7FFFu + ((v.u >> 16) & 1u)) >> 16);  // RNE
}

#define AS_G(p) ((const __attribute__((address_space(1))) void*)(p))
#define AS_L(p) ((__attribute__((address_space(3))) void*)(p))

// ---------------- prep: x->bf16; w1,w2 -> bf16 [e][n][k]; zero BN stats ------
__global__ __launch_bounds__(256) void prep_kernel(
    const float* __restrict__ x, const float* __restrict__ w1,
    const float* __restrict__ w2, u16* __restrict__ xb,
    u16* __restrict__ w1t, u16* __restrict__ w2t, float* __restrict__ stats)
{
  int bid = blockIdx.x, t = threadIdx.x;
  __shared__ float ld[64][65];   // +1 pad breaks col-read conflicts
  if (bid >= 1152) {             // zero 8KB of BN accumulators (sS + sQ)
    f32x4 z = {0, 0, 0, 0};
    *(f32x4*)(stats + t * 8) = z;
    *(f32x4*)(stats + t * 8 + 4) = z;
    return;
  }
  if (bid < 128) {               // convert x
    int p = (bid * 256 + t) * 16;
    #pragma unroll
    for (int i = 0; i < 4; ++i) {
      f32x4 v = *(const f32x4*)(x + p + i * 4);
      u16x4 o;
      o.x = f2bf(v.x); o.y = f2bf(v.y); o.z = f2bf(v.z); o.w = f2bf(v.w);
      *(u16x4*)(xb + p + i * 4) = o;
    }
    return;
  }
  int b2 = bid - 128;                        // 1024 blocks: 2 weights * 8 e * 64 tiles
  const float* src = (b2 >> 9) ? w2 : w1;
  u16* dst = (b2 >> 9) ? w2t : w1t;
  int rem = b2 & 511;
  int e = rem >> 6, tl = rem & 63;
  int kt = tl >> 3, nt = tl & 7;             // 64x64 tile at (kt,nt)
  #pragma unroll
  for (int j = 0; j < 4; ++j) {              // read [k][n] coalesced
    int kr = j * 16 + (t >> 4), nc = (t & 15) * 4;
    f32x4 v = *(const f32x4*)(src + (size_t)((e * 512 + kt * 64 + kr)) * 512 + nt * 64 + nc);
    ld[kr][nc] = v.x; ld[kr][nc + 1] = v.y; ld[kr][nc + 2] = v.z; ld[kr][nc + 3] = v.w;
  }
  __syncthreads();
  #pragma unroll
  for (int j = 0; j < 4; ++j) {              // write [n][k] coalesced, bf16
    int nr = j * 16 + (t >> 4), kc = (t & 15) * 4;
    u16x4 o;
    o.x = f2bf(ld[kc][nr]);     o.y = f2bf(ld[kc + 1][nr]);
    o.z = f2bf(ld[kc + 2][nr]); o.w = f2bf(ld[kc + 3][nr]);
    *(u16x4*)(dst + (size_t)((e * 512 + nt * 64 + nr)) * 512 + kt * 64 + kc) = o;
  }
}

// ---------------- per-expert GEMM: P[e] = A @ W[e], 64x64 tile, BK=64 -------
// LDS swizzle: physical_chunk = logical_chunk ^ (row&7)  (chunk = 8 bf16 = 16B)
//   -> bank = f(chunk) only, fragment reads 2-way (free).
// global_load_lds writes linearly, so the SOURCE is pre-swizzled:
//   lane l of an 8-row issue fetches global chunk (l&7)^(l>>3) of row rb+(l>>3).
// LAYER 1: A = xb (bf16) staged via global_load_lds.
// LAYER 2: A = elu(BN(h)) computed in registers, linear ds_write (conflict-free).
template <int LAYER>
__global__ __launch_bounds__(256) void gemm_expert(
    const u16* __restrict__ Axb, const float* __restrict__ H,
    const u16* __restrict__ Wt,
    const float* __restrict__ sS, const float* __restrict__ sQ,
    const float* __restrict__ gamma, const float* __restrict__ beta,
    float* __restrict__ P)
{
  int bid = blockIdx.x;                      // 1024 blocks
  int e = bid & 7;                           // expert == XCD (round-robin heuristic)
  int tile = bid >> 3, mt = tile >> 3, nt = tile & 7;
  int t = threadIdx.x, l = t & 63, w = t >> 6;
  int wm = w >> 1, wn = w & 1;               // 2x2 waves, 32x32 each

  __shared__ alignas(16) u16 As[64 * 64];    // 8 KB, swizzled layout
  __shared__ alignas(16) u16 Bs[64 * 64];    // 8 KB, swizzled layout
  __shared__ float scale_s[512], shift_s[512];

  if constexpr (LAYER == 2) {                // finalize BN params once per block
    for (int c = t; c < 512; c += 256) {
      float S = sS[c], Q = sQ[c];
      float mean = S * (1.0f / 1024.0f);
      float var  = Q * (1.0f / 1024.0f) - mean * mean;   // biased, matches ref
      float sc = gamma[c] * rsqrtf(var + 1e-5f);
      scale_s[c] = sc; shift_s[c] = beta[c] - mean * sc;
    }
    __syncthreads();
  }

  f32x4 acc[2][2] = {};
  const u16* Bg = Wt + (size_t)(e * 512 + nt * 64) * 512;
  int lr = l >> 3;
  int swz = ((l & 7) ^ lr) * 8;              // pre-swizzled source chunk (elems)

  for (int kt = 0; kt < 8; ++kt) {
    int k0 = kt * 64;
    #pragma unroll
    for (int j = 0; j < 2; ++j) {            // stage B (2 issues/wave x 8 rows)
      int rb = w * 16 + j * 8;
      __builtin_amdgcn_global_load_lds(AS_G(Bg + (size_t)(rb + lr) * 512 + k0 + swz),
                                       AS_L(&Bs[rb * 64]), 16, 0, 0);
    }
    if constexpr (LAYER == 1) {
      #pragma unroll
      for (int j = 0; j < 2; ++j) {          // stage A from xb
        int rb = w * 16 + j * 8;
        __builtin_amdgcn_global_load_lds(AS_G(Axb + (size_t)(mt * 64 + rb + lr) * 512 + k0 + swz),
                                         AS_L(&As[rb * 64]), 16, 0, 0);
      }
    } else {
      #pragma unroll
      for (int pj = 0; pj < 2; ++pj) {       // reg-stage h + BN + ELU + cast
        int p = pj * 256 + t;                // physical chunk id (512 total)
        int row = p >> 3;
        int cl = (p & 7) ^ (row & 7);        // logical chunk at this phys slot
        const float* hsrc = H + (size_t)(mt * 64 + row) * 512 + k0 + cl * 8;
        f32x4 v0 = *(const f32x4*)hsrc;
        f32x4 v1 = *(const f32x4*)(hsrc + 4);
        f32x4 s0 = *(const f32x4*)(scale_s + k0 + cl * 8);
        f32x4 s1 = *(const f32x4*)(scale_s + k0 + cl * 8 + 4);
        f32x4 f0 = *(const f32x4*)(shift_s + k0 + cl * 8);
        f32x4 f1 = *(const f32x4*)(shift_s + k0 + cl * 8 + 4);
        u16x8 o;
        #pragma unroll
        for (int i = 0; i < 4; ++i) {
          float hn = v0[i] * s0[i] + f0[i];
          o[i] = f2bf(hn > 0.0f ? hn : expm1f(hn));
        }
        #pragma unroll
        for (int i = 0; i < 4; ++i) {
          float hn = v1[i] * s1[i] + f1[i];
          o[4 + i] = f2bf(hn > 0.0f ? hn : expm1f(hn));
        }
        *(u16x8*)&As[p * 8] = o;             // linear b128 write: conflict-free
      }
    }
    __syncthreads();                         // drains vmcnt (DMA) + lgkm (writes)
    #pragma unroll
    for (int kk = 0; kk < 2; ++kk) {
      int c = kk * 4 + (l >> 4);             // logical chunk for this fragment
      bf16x8 af[2], bb[2];
      #pragma unroll
      for (int m = 0; m < 2; ++m) {
        int row = wm * 32 + m * 16 + (l & 15);
        af[m] = *(const bf16x8*)&As[row * 64 + ((c ^ (row & 7)) << 3)];
      }
      #pragma unroll
      for (int n = 0; n < 2; ++n) {
        int row = wn * 32 + n * 16 + (l & 15);
        bb[n] = *(const bf16x8*)&Bs[row * 64 + ((c ^ (row & 7)) << 3)];
      }
      #pragma unroll
      for (int m = 0; m < 2; ++m)
        #pragma unroll
        for (int n = 0; n < 2; ++n)
          acc[m][n] = __builtin_amdgcn_mfma_f32_16x16x32_bf16(af[m], bb[n], acc[m][n], 0, 0, 0);
    }
    __syncthreads();                         // LDS reads done before restage
  }
  // epilogue: C/D layout col=lane&15, row=(lane>>4)*4+reg (HW-verified)
  float* Pe = P + (size_t)((e << 10) + mt * 64 + wm * 32) * 512 + nt * 64 + wn * 32;
  #pragma unroll
  for (int m = 0; m < 2; ++m)
    #pragma unroll
    for (int n = 0; n < 2; ++n) {
      int col = n * 16 + (l & 15);
      int rbase = m * 16 + (l >> 4) * 4;
      #pragma unroll
      for (int r = 0; r < 4; ++r)
        Pe[(size_t)(rbase + r) * 512 + col] = acc[m][n][r];
    }
}

// ---------------- blend-reduce: out = sum_e coef*(P[e]+bias[e]); opt BN stats --
template <int STATS>
__global__ __launch_bounds__(256) void blend_kernel(
    const float* __restrict__ P, const float* __restrict__ coef,
    const float* __restrict__ bias, float* __restrict__ out,
    float* __restrict__ sSum, float* __restrict__ sSq)
{
  int bid = blockIdx.x;                      // 128 blocks: 64 row-blks x 2 col-blks
  int mblk = bid >> 1, cblk = bid & 1;
  int t = threadIdx.x, w = t >> 6, cg = t & 63;
  int col = cblk * 256 + cg * 4;
  f32x4 ssum = {0, 0, 0, 0}, ssq = {0, 0, 0, 0};
  #pragma unroll
  for (int rj = 0; rj < 4; ++rj) {
    int row = mblk * 16 + rj * 4 + w;
    const float* cr = coef + row * 8;
    f32x4 acc = {0, 0, 0, 0};
    #pragma unroll
    for (int e = 0; e < 8; ++e) {
      float c = cr[e];
      f32x4 p = *(const f32x4*)(P + (size_t)((e << 10) + row) * 512 + col);
      f32x4 bb = *(const f32x4*)(bias + e * 512 + col);
      acc += c * (p + bb);
    }
    *(f32x4*)(out + (size_t)row * 512 + col) = acc;
    if constexpr (STATS) { ssum += acc; ssq += acc * acc; }
  }
  if constexpr (STATS) {
    __shared__ f32x4 red[2][4][64];
    red[0][w][cg] = ssum; red[1][w][cg] = ssq;
    __syncthreads();
    if (w == 0) {
      #pragma unroll
      for (int wv = 1; wv < 4; ++wv) { ssum += red[0][wv][cg]; ssq += red[1][wv][cg]; }
      #pragma unroll
      for (int i = 0; i < 4; ++i) {
        atomicAdd(&sSum[col + i], ssum[i]);
        atomicAdd(&sSq[col + i], ssq[i]);
      }
    }
  }
}

extern "C" void kernel_launch(void* const* d_in, const int* in_sizes, int n_in,
                              void* d_out, int out_size, void* d_ws, size_t ws_size,
                              hipStream_t stream)
{
  const float* x     = (const float*)d_in[0];
  const float* coef  = (const float*)d_in[1];
  const float* w1    = (const float*)d_in[2];
  const float* b1    = (const float*)d_in[3];
  const float* w2    = (const float*)d_in[4];
  const float* b2    = (const float*)d_in[5];
  const float* gamma = (const float*)d_in[6];
  const float* beta  = (const float*)d_in[7];
  float* out = (float*)d_out;

  char* ws = (char*)d_ws;
  u16* w1t  = (u16*)(ws);                          //  4 MB [8][512n][512k] bf16
  u16* w2t  = (u16*)(ws + (4u << 20));             //  4 MB
  u16* xb   = (u16*)(ws + (8u << 20));             //  1 MB [1024][512] bf16
  float* h  = (float*)(ws + (9u << 20));           //  2 MB [1024][512] f32
  float* prt= (float*)(ws + (11u << 20));          // 16 MB [8][1024][512] f32
  float* sS = (float*)(ws + (27u << 20));          //  2 KB col sums
  float* sQ = (float*)(ws + (27u << 20) + 4096);   //  2 KB col sumsq

  prep_kernel<<<1153, 256, 0, stream>>>(x, w1, w2, xb, w1t, w2t, sS);
  gemm_expert<1><<<1024, 256, 0, stream>>>(xb, nullptr, w1t, nullptr, nullptr,
                                           nullptr, nullptr, prt);
  blend_kernel<1><<<128, 256, 0, stream>>>(prt, coef, b1, h, sS, sQ);
  gemm_expert<2><<<1024, 256, 0, stream>>>(nullptr, h, w2t, sS, sQ,
                                           gamma, beta, prt);
  blend_kernel<0><<<128, 256, 0, stream>>>(prt, coef, b2, out, nullptr, nullptr);
}